// Round 9
// baseline (244.029 us; speedup 1.0000x reference)
//
#include <hip/hip_runtime.h>
#include <hip/hip_fp16.h>

// SSIM, fused separable-conv single pass + reduce.
// x,y: [16,3,512,512] f32; window: [3,1,11,11] f32 (separable Gaussian).
// Output: scalar mean SSIM (f32).
//
// V8 = V7 with phase-H's lambda replaced by a MACRO (guaranteed inline).
// Scratch forensics across rounds: V5/V6 spilled `unsigned A[12]` (48 B/thr
// -> 150 MB WRITE). V7 removed the array but introduced `auto hconv = [&]`
// with reference out-params, called 5x: when the inliner declines (large
// body), captures go through a frame pointer -> the 20 output floats + g2 +
// hnorm live in a scratch frame (~55 B/thr -> 173 MB WRITE, VGPR stuck at
// 40, VALUBusy 52%). A macro has no captures, no frame, no references:
// everything stays in named VGPRs.
//
// Proven content kept: vv stored f16 (RTNE, unbiased); H-conv via
// v_dot2_f32_f16 (f32 accum, products exact); f16-tap renormalization
// h/Sum(h) (kills V3's 4.9e-4 bias); SSIM division via v_rcp_f32
// (den >= 9e-8); phase V direct global loads, f32 taps/accum (this exact
// phase-V compiled spill-free in V2b at 40 VGPRs);
// __launch_bounds__(256,6) (V4's (256,8) forced a 64-VGPR pressure spill).

#define IMG_H 512
#define IMG_W 512
#define NC    48            // 16 batches * 3 channels

constexpr int TW = 64;      // output tile width
constexpr int TH = 16;      // output tile height
constexpr int NBLK = (IMG_W / TW) * (IMG_H / TH) * NC;   // 12288

typedef _Float16 v2h __attribute__((ext_vector_type(2)));

static __device__ __forceinline__ v2h as_h2(unsigned u) {
    union { unsigned u; v2h h; } x; x.u = u; return x.h;
}

__global__ __launch_bounds__(256, 6)
void ssim_fused(const float* __restrict__ x, const float* __restrict__ y,
                const float* __restrict__ w, double* __restrict__ part,
                int use_atomic)
{
    // f16 vconv planes: 80 halves/row = 160 B. Cols 0..74 from phase V,
    // col 75 zeroed (touched by zero-coefficient dot2 pairs), 76..79 unused.
    __shared__ __align__(16) __half vvH[5][TH][80];
    __shared__ float wsum[4];

    const int tid = threadIdx.x;
    const int x0 = blockIdx.x * TW - 8;    // virtual staged col 0
    const int y0 = blockIdx.y * TH - 5;    // virtual staged row 0
    const float* __restrict__ xp = x + (size_t)blockIdx.z * (IMG_H * IMG_W);
    const float* __restrict__ yp = y + (size_t)blockIdx.z * (IMG_H * IMG_W);

    // 1D gaussian from window row 5: g[k] = w[55+k]/sqrt(w[60]).
    float g[11];
    {
        const float g5inv = 1.0f / sqrtf(w[55 + 5]);
        #pragma unroll
        for (int k = 0; k < 11; ++k)
            g[k] = __uint_as_float(
                (unsigned)__builtin_amdgcn_readfirstlane(
                    (int)__float_as_uint(w[55 + k] * g5inv)));
    }
    // Named half2 tap pairs + exact f32 sum of rounded taps (renormalizer).
    const v2h g2_0 = v2h{(_Float16)g[0], (_Float16)g[1]};
    const v2h g2_1 = v2h{(_Float16)g[2], (_Float16)g[3]};
    const v2h g2_2 = v2h{(_Float16)g[4], (_Float16)g[5]};
    const v2h g2_3 = v2h{(_Float16)g[6], (_Float16)g[7]};
    const v2h g2_4 = v2h{(_Float16)g[8], (_Float16)g[9]};
    const v2h g2_5 = v2h{(_Float16)g[10], (_Float16)0.0f};
    const float hsum =
        (float)g2_0.x + (float)g2_0.y + (float)g2_1.x + (float)g2_1.y +
        (float)g2_2.x + (float)g2_2.y + (float)g2_3.x + (float)g2_3.y +
        (float)g2_4.x + (float)g2_4.y + (float)g2_5.x;
    const float hnorm = 1.0f / hsum;               // uniform, once per block

    // Accessed region: rows y0 .. y0+25, cols x0+2 .. x0+76.
    const bool interior = (y0 >= 0) & (y0 + 25 < IMG_H)
                        & (x0 + 2 >= 0) & (x0 + 76 < IMG_W);

    // ---- Phase V: vertical 11-tap conv of {x,y,xx,yy,xy} at image col
    //      x0+c+2, 4-row register blocking, inputs straight from global.
    //      Results stored to LDS as f16 (RTNE).
    for (int t = tid; t < 75 * 4; t += 256) {
        const int c   = t % 75;
        const int r0  = (t / 75) << 2;
        const int gc  = x0 + c + 2;
        const int gr0 = y0 + r0;
        float xv[14], yv[14], xxv[14], yyv[14], xyv[14];
        if (interior) {
            const unsigned base = (unsigned)(gr0 * IMG_W + gc);
            #pragma unroll
            for (int k = 0; k < 14; ++k) {
                const float a = xp[base + (unsigned)(k * IMG_W)];
                const float b = yp[base + (unsigned)(k * IMG_W)];
                xv[k] = a; yv[k] = b;
                xxv[k] = a * a; yyv[k] = b * b; xyv[k] = a * b;
            }
        } else {
            const int  cc  = min(max(gc, 0), IMG_W - 1);
            const bool okc = ((unsigned)gc < (unsigned)IMG_W);
            #pragma unroll
            for (int k = 0; k < 14; ++k) {
                const int  gr = gr0 + k;
                const int  cr = min(max(gr, 0), IMG_H - 1);
                const bool ok = okc & ((unsigned)gr < (unsigned)IMG_H);
                const unsigned idx = (unsigned)(cr * IMG_W + cc);
                const float a = ok ? xp[idx] : 0.0f;   // zero padding
                const float b = ok ? yp[idx] : 0.0f;
                xv[k] = a; yv[k] = b;
                xxv[k] = a * a; yyv[k] = b * b; xyv[k] = a * b;
            }
        }
        #pragma unroll
        for (int j = 0; j < 4; ++j) {
            float s0 = 0.f, s1 = 0.f, s2 = 0.f, s3 = 0.f, s4 = 0.f;
            #pragma unroll
            for (int k = 0; k < 11; ++k) {
                const float gk = g[k];
                s0 = fmaf(gk, xv[j + k],  s0);
                s1 = fmaf(gk, yv[j + k],  s1);
                s2 = fmaf(gk, xxv[j + k], s2);
                s3 = fmaf(gk, yyv[j + k], s3);
                s4 = fmaf(gk, xyv[j + k], s4);
            }
            vvH[0][r0 + j][c] = __float2half(s0);
            vvH[1][r0 + j][c] = __float2half(s1);
            vvH[2][r0 + j][c] = __float2half(s2);
            vvH[3][r0 + j][c] = __float2half(s3);
            vvH[4][r0 + j][c] = __float2half(s4);
        }
    }
    // col 75 is consumed (x 0 coeff) by dot2 pairs -> must be finite
    if (tid < 80) vvH[tid >> 4][tid & 15][75] = __half(0.0f);
    __syncthreads();

    // ---- Phase H: horizontal 11-tap conv via dot2 + SSIM.
    // Thread -> (row r, 4-col group i). Output col j = 4i+t taps vv cols
    // j+1..j+11. u32 word m of the row holds cols (2m, 2m+1). Words
    // 2i..2i+7 needed (+1 for shifts); base w0 = 4*(i>>1) (16B aligned),
    // odd parity via named cndmask selects. MACRO = textual inline: no
    // lambda frame, no captures, no references -> all VGPR.
    const int r   = tid >> 4;           // 0..15
    const int i   = tid & 15;           // 0..15
    const int w0  = (i >> 1) << 2;      // u32 word base, 16B aligned
    const bool odd = (i & 1) != 0;

    float m1_0, m1_1, m1_2, m1_3;
    float m2_0, m2_1, m2_2, m2_3;
    float xx0, xx1, xx2, xx3;
    float yy0, yy1, yy2, yy3;
    float xy0, xy1, xy2, xy3;

#define HSTEP(GP, WS, WB1, WS1, WB2) \
        a0 = __builtin_amdgcn_fdot2(as_h2(WS),  GP, a0, false); \
        a1 = __builtin_amdgcn_fdot2(as_h2(WB1), GP, a1, false); \
        a2 = __builtin_amdgcn_fdot2(as_h2(WS1), GP, a2, false); \
        a3 = __builtin_amdgcn_fdot2(as_h2(WB2), GP, a3, false);

#define HCONV(PLANE, O0, O1, O2, O3) { \
        const unsigned* rowp = (const unsigned*)&vvH[PLANE][r][0]; \
        const uint4 A0 = *(const uint4*)(rowp + w0); \
        const uint4 A1 = *(const uint4*)(rowp + w0 + 4); \
        const uint2 A2 = *(const uint2*)(rowp + w0 + 8); \
        const unsigned u0 = A0.x, u1 = A0.y, u2 = A0.z, u3 = A0.w; \
        const unsigned u4 = A1.x, u5 = A1.y, u6 = A1.z, u7 = A1.w; \
        const unsigned u8 = A2.x, u9 = A2.y; \
        const unsigned b0 = odd ? u2 : u0, b1 = odd ? u3 : u1; \
        const unsigned b2 = odd ? u4 : u2, b3 = odd ? u5 : u3; \
        const unsigned b4 = odd ? u6 : u4, b5 = odd ? u7 : u5; \
        const unsigned b6 = odd ? u8 : u6, b7 = odd ? u9 : u7; \
        const unsigned s0 = (b0 >> 16) | (b1 << 16); \
        const unsigned s1 = (b1 >> 16) | (b2 << 16); \
        const unsigned s2 = (b2 >> 16) | (b3 << 16); \
        const unsigned s3 = (b3 >> 16) | (b4 << 16); \
        const unsigned s4 = (b4 >> 16) | (b5 << 16); \
        const unsigned s5 = (b5 >> 16) | (b6 << 16); \
        const unsigned s6 = (b6 >> 16) | (b7 << 16); \
        float a0 = 0.f, a1 = 0.f, a2 = 0.f, a3 = 0.f; \
        HSTEP(g2_0, s0, b1, s1, b2) \
        HSTEP(g2_1, s1, b2, s2, b3) \
        HSTEP(g2_2, s2, b3, s3, b4) \
        HSTEP(g2_3, s3, b4, s4, b5) \
        HSTEP(g2_4, s4, b5, s5, b6) \
        HSTEP(g2_5, s5, b6, s6, b7) \
        O0 = a0 * hnorm; O1 = a1 * hnorm; \
        O2 = a2 * hnorm; O3 = a3 * hnorm; }

    HCONV(0, m1_0, m1_1, m1_2, m1_3)
    HCONV(1, m2_0, m2_1, m2_2, m2_3)
    HCONV(2, xx0, xx1, xx2, xx3)
    HCONV(3, yy0, yy1, yy2, yy3)
    HCONV(4, xy0, xy1, xy2, xy3)
#undef HCONV
#undef HSTEP

    const float C1 = 1e-4f;   // 0.01^2
    const float C2 = 9e-4f;   // 0.03^2
    float local = 0.0f;
#define SSIM_T(M1, M2, XX, YY, XY) { \
        const float m1s = (M1) * (M1), m2s = (M2) * (M2), m12 = (M1) * (M2); \
        const float num = (2.0f * m12 + C1) * (2.0f * ((XY) - m12) + C2);    \
        const float den = (m1s + m2s + C1) * (((XX) - m1s) + ((YY) - m2s) + C2); \
        local += num * __builtin_amdgcn_rcpf(den); }   /* den >= 9e-8 */
    SSIM_T(m1_0, m2_0, xx0, yy0, xy0)
    SSIM_T(m1_1, m2_1, xx1, yy1, xy1)
    SSIM_T(m1_2, m2_2, xx2, yy2, xy2)
    SSIM_T(m1_3, m2_3, xx3, yy3, xy3)
#undef SSIM_T

    // ---- Block reduction: wave shuffle -> LDS -> one store (or atomic) per block
    #pragma unroll
    for (int off = 32; off > 0; off >>= 1)
        local += __shfl_down(local, off, 64);
    if ((tid & 63) == 0) wsum[tid >> 6] = local;
    __syncthreads();
    if (tid == 0) {
        const double blk = (double)wsum[0] + (double)wsum[1]
                         + (double)wsum[2] + (double)wsum[3];
        if (use_atomic) {
            atomicAdd(part, blk);
        } else {
            const int bflat = blockIdx.x
                            + gridDim.x * (blockIdx.y + gridDim.y * blockIdx.z);
            part[bflat] = blk;
        }
    }
}

__global__ void ssim_reduce(const double* __restrict__ part, float* __restrict__ out,
                            int n)
{
    __shared__ double s[256];
    double t = 0.0;
    for (int i = threadIdx.x; i < n; i += 256) t += part[i];
    s[threadIdx.x] = t;
    __syncthreads();
    for (int off = 128; off > 0; off >>= 1) {
        if (threadIdx.x < off) s[threadIdx.x] += s[threadIdx.x + off];
        __syncthreads();
    }
    if (threadIdx.x == 0)
        out[0] = (float)(s[0] / (double)((size_t)NC * IMG_H * IMG_W));
}

extern "C" void kernel_launch(void* const* d_in, const int* in_sizes, int n_in,
                              void* d_out, int out_size, void* d_ws, size_t ws_size,
                              hipStream_t stream)
{
    const float* x = (const float*)d_in[0];
    const float* y = (const float*)d_in[1];
    const float* w = (const float*)d_in[2];
    double* part = (double*)d_ws;

    const bool fits = ws_size >= (size_t)NBLK * sizeof(double);
    dim3 grid(IMG_W / TW, IMG_H / TH, NC);   // (8, 32, 48) = 12288 blocks

    if (fits) {
        // every block writes its own slot; no memset, no atomics
        ssim_fused<<<grid, 256, 0, stream>>>(x, y, w, part, 0);
        ssim_reduce<<<1, 256, 0, stream>>>(part, (float*)d_out, NBLK);
    } else {
        hipMemsetAsync(d_ws, 0, sizeof(double), stream);
        ssim_fused<<<grid, 256, 0, stream>>>(x, y, w, part, 1);
        ssim_reduce<<<1, 256, 0, stream>>>(part, (float*)d_out, 1);
    }
}

// Round 10
// 241.893 us; speedup vs baseline: 1.0088x; 1.0088x over previous
//
#include <hip/hip_runtime.h>

// SSIM, fused separable-conv single pass + reduce.
// x,y: [16,3,512,512] f32; window: [3,1,11,11] f32 (separable Gaussian).
// Output: scalar mean SSIM (f32).
//
// V9: f16 path rewritten with NO classes, NO unions, NO struct loads.
// Scratch forensics: V5-V8 all showed ~55 B/thread scratch (150-173 MB
// WRITE_SIZE) across three different phase-H forms -> the alloca is in a
// construct COMMON to all f16 variants and absent from spill-free V2b.
// Suspects eliminated this round: __half class stores (phase V temporaries),
// the as_h2 union (memory-typed punning x120/thread). Now:
//   - LDS planes are raw `unsigned short`
//   - f16 convert+store via __builtin_bit_cast(ushort,(_Float16)s)  [RTNE]
//   - u32 pair -> half2 via __builtin_bit_cast(v2h, u)              [SSA]
//   - LDS reads via ext_vector u32x4/u32x2 (no struct members)
// Proven content kept: H-conv via v_dot2_f32_f16 (f32 accum, products
// exact); f16-tap renormalization h/Sum(h) (kills V3's 4.9e-4 bias); SSIM
// division via v_rcp_f32 (den >= 9e-8); phase V direct global loads, f32
// taps/accum (spill-free in V2b at 40 VGPR); __launch_bounds__(256,6).

#define IMG_H 512
#define IMG_W 512
#define NC    48            // 16 batches * 3 channels

constexpr int TW = 64;      // output tile width
constexpr int TH = 16;      // output tile height
constexpr int NBLK = (IMG_W / TW) * (IMG_H / TH) * NC;   // 12288

typedef _Float16 v2h   __attribute__((ext_vector_type(2)));
typedef unsigned u32x4 __attribute__((ext_vector_type(4)));
typedef unsigned u32x2 __attribute__((ext_vector_type(2)));

static __device__ __forceinline__ v2h as_h2(unsigned u) {
    return __builtin_bit_cast(v2h, u);
}
static __device__ __forceinline__ unsigned short f16bits(float f) {
    return __builtin_bit_cast(unsigned short, (_Float16)f);   // RTNE cvt
}

__global__ __launch_bounds__(256, 6)
void ssim_fused(const float* __restrict__ x, const float* __restrict__ y,
                const float* __restrict__ w, double* __restrict__ part,
                int use_atomic)
{
    // f16 vconv planes as raw ushort: 80 halves/row = 160 B. Cols 0..74 from
    // phase V, col 75 zeroed (touched by zero-coeff dot2 pairs), 76..79 unused.
    __shared__ __align__(16) unsigned short vvS[5][TH][80];
    __shared__ float wsum[4];

    const int tid = threadIdx.x;
    const int x0 = blockIdx.x * TW - 8;    // virtual staged col 0
    const int y0 = blockIdx.y * TH - 5;    // virtual staged row 0
    const float* __restrict__ xp = x + (size_t)blockIdx.z * (IMG_H * IMG_W);
    const float* __restrict__ yp = y + (size_t)blockIdx.z * (IMG_H * IMG_W);

    // 1D gaussian from window row 5: g[k] = w[55+k]/sqrt(w[60]).
    float g[11];
    {
        const float g5inv = 1.0f / sqrtf(w[55 + 5]);
        #pragma unroll
        for (int k = 0; k < 11; ++k)
            g[k] = __uint_as_float(
                (unsigned)__builtin_amdgcn_readfirstlane(
                    (int)__float_as_uint(w[55 + k] * g5inv)));
    }
    // Named half2 tap pairs (vector literals, no class) + exact f32 sum of
    // the rounded taps for renormalization.
    const v2h g2_0 = v2h{(_Float16)g[0], (_Float16)g[1]};
    const v2h g2_1 = v2h{(_Float16)g[2], (_Float16)g[3]};
    const v2h g2_2 = v2h{(_Float16)g[4], (_Float16)g[5]};
    const v2h g2_3 = v2h{(_Float16)g[6], (_Float16)g[7]};
    const v2h g2_4 = v2h{(_Float16)g[8], (_Float16)g[9]};
    const v2h g2_5 = v2h{(_Float16)g[10], (_Float16)0.0f};
    const float hsum =
        (float)g2_0[0] + (float)g2_0[1] + (float)g2_1[0] + (float)g2_1[1] +
        (float)g2_2[0] + (float)g2_2[1] + (float)g2_3[0] + (float)g2_3[1] +
        (float)g2_4[0] + (float)g2_4[1] + (float)g2_5[0];
    const float hnorm = 1.0f / hsum;               // uniform, once per block

    // Accessed region: rows y0 .. y0+25, cols x0+2 .. x0+76.
    const bool interior = (y0 >= 0) & (y0 + 25 < IMG_H)
                        & (x0 + 2 >= 0) & (x0 + 76 < IMG_W);

    // ---- Phase V: vertical 11-tap conv of {x,y,xx,yy,xy} at image col
    //      x0+c+2, 4-row register blocking, inputs straight from global.
    //      Results stored to LDS as f16 bits (RTNE scalar cvt, no class).
    for (int t = tid; t < 75 * 4; t += 256) {
        const int c   = t % 75;
        const int r0  = (t / 75) << 2;
        const int gc  = x0 + c + 2;
        const int gr0 = y0 + r0;
        float xv[14], yv[14], xxv[14], yyv[14], xyv[14];
        if (interior) {
            const unsigned base = (unsigned)(gr0 * IMG_W + gc);
            #pragma unroll
            for (int k = 0; k < 14; ++k) {
                const float a = xp[base + (unsigned)(k * IMG_W)];
                const float b = yp[base + (unsigned)(k * IMG_W)];
                xv[k] = a; yv[k] = b;
                xxv[k] = a * a; yyv[k] = b * b; xyv[k] = a * b;
            }
        } else {
            const int  cc  = min(max(gc, 0), IMG_W - 1);
            const bool okc = ((unsigned)gc < (unsigned)IMG_W);
            #pragma unroll
            for (int k = 0; k < 14; ++k) {
                const int  gr = gr0 + k;
                const int  cr = min(max(gr, 0), IMG_H - 1);
                const bool ok = okc & ((unsigned)gr < (unsigned)IMG_H);
                const unsigned idx = (unsigned)(cr * IMG_W + cc);
                const float a = ok ? xp[idx] : 0.0f;   // zero padding
                const float b = ok ? yp[idx] : 0.0f;
                xv[k] = a; yv[k] = b;
                xxv[k] = a * a; yyv[k] = b * b; xyv[k] = a * b;
            }
        }
        #pragma unroll
        for (int j = 0; j < 4; ++j) {
            float s0 = 0.f, s1 = 0.f, s2 = 0.f, s3 = 0.f, s4 = 0.f;
            #pragma unroll
            for (int k = 0; k < 11; ++k) {
                const float gk = g[k];
                s0 = fmaf(gk, xv[j + k],  s0);
                s1 = fmaf(gk, yv[j + k],  s1);
                s2 = fmaf(gk, xxv[j + k], s2);
                s3 = fmaf(gk, yyv[j + k], s3);
                s4 = fmaf(gk, xyv[j + k], s4);
            }
            vvS[0][r0 + j][c] = f16bits(s0);
            vvS[1][r0 + j][c] = f16bits(s1);
            vvS[2][r0 + j][c] = f16bits(s2);
            vvS[3][r0 + j][c] = f16bits(s3);
            vvS[4][r0 + j][c] = f16bits(s4);
        }
    }
    // col 75 is consumed (x 0 coeff) by dot2 pairs -> must be finite (+0.0)
    if (tid < 80) vvS[tid >> 4][tid & 15][75] = 0;
    __syncthreads();

    // ---- Phase H: horizontal 11-tap conv via dot2 + SSIM.
    // Thread -> (row r, 4-col group i). Output col j = 4i+t taps vv cols
    // j+1..j+11. u32 word m of the row holds cols (2m, 2m+1). Words
    // 2i..2i+7 needed (+1 for shifts); base w0 = 4*(i>>1) (16B aligned),
    // odd parity via named cndmask selects. Everything is a named SSA
    // scalar / ext_vector: no alloca anywhere.
    const int r   = tid >> 4;           // 0..15
    const int i   = tid & 15;           // 0..15
    const int w0  = (i >> 1) << 2;      // u32 word base, 16B aligned
    const bool odd = (i & 1) != 0;

    float m1_0, m1_1, m1_2, m1_3;
    float m2_0, m2_1, m2_2, m2_3;
    float xx0, xx1, xx2, xx3;
    float yy0, yy1, yy2, yy3;
    float xy0, xy1, xy2, xy3;

#define HSTEP(GP, WS, WB1, WS1, WB2) \
        a0 = __builtin_amdgcn_fdot2(as_h2(WS),  GP, a0, false); \
        a1 = __builtin_amdgcn_fdot2(as_h2(WB1), GP, a1, false); \
        a2 = __builtin_amdgcn_fdot2(as_h2(WS1), GP, a2, false); \
        a3 = __builtin_amdgcn_fdot2(as_h2(WB2), GP, a3, false);

#define HCONV(PLANE, O0, O1, O2, O3) { \
        const unsigned* rowp = (const unsigned*)&vvS[PLANE][r][0]; \
        const u32x4 A0 = *(const u32x4*)(rowp + w0); \
        const u32x4 A1 = *(const u32x4*)(rowp + w0 + 4); \
        const u32x2 A2 = *(const u32x2*)(rowp + w0 + 8); \
        const unsigned u0 = A0[0], u1 = A0[1], u2 = A0[2], u3 = A0[3]; \
        const unsigned u4 = A1[0], u5 = A1[1], u6 = A1[2], u7 = A1[3]; \
        const unsigned u8 = A2[0], u9 = A2[1]; \
        const unsigned b0 = odd ? u2 : u0, b1 = odd ? u3 : u1; \
        const unsigned b2 = odd ? u4 : u2, b3 = odd ? u5 : u3; \
        const unsigned b4 = odd ? u6 : u4, b5 = odd ? u7 : u5; \
        const unsigned b6 = odd ? u8 : u6, b7 = odd ? u9 : u7; \
        const unsigned s0 = (b0 >> 16) | (b1 << 16); \
        const unsigned s1 = (b1 >> 16) | (b2 << 16); \
        const unsigned s2 = (b2 >> 16) | (b3 << 16); \
        const unsigned s3 = (b3 >> 16) | (b4 << 16); \
        const unsigned s4 = (b4 >> 16) | (b5 << 16); \
        const unsigned s5 = (b5 >> 16) | (b6 << 16); \
        const unsigned s6 = (b6 >> 16) | (b7 << 16); \
        float a0 = 0.f, a1 = 0.f, a2 = 0.f, a3 = 0.f; \
        HSTEP(g2_0, s0, b1, s1, b2) \
        HSTEP(g2_1, s1, b2, s2, b3) \
        HSTEP(g2_2, s2, b3, s3, b4) \
        HSTEP(g2_3, s3, b4, s4, b5) \
        HSTEP(g2_4, s4, b5, s5, b6) \
        HSTEP(g2_5, s5, b6, s6, b7) \
        O0 = a0 * hnorm; O1 = a1 * hnorm; \
        O2 = a2 * hnorm; O3 = a3 * hnorm; }

    HCONV(0, m1_0, m1_1, m1_2, m1_3)
    HCONV(1, m2_0, m2_1, m2_2, m2_3)
    HCONV(2, xx0, xx1, xx2, xx3)
    HCONV(3, yy0, yy1, yy2, yy3)
    HCONV(4, xy0, xy1, xy2, xy3)
#undef HCONV
#undef HSTEP

    const float C1 = 1e-4f;   // 0.01^2
    const float C2 = 9e-4f;   // 0.03^2
    float local = 0.0f;
#define SSIM_T(M1, M2, XX, YY, XY) { \
        const float m1s = (M1) * (M1), m2s = (M2) * (M2), m12 = (M1) * (M2); \
        const float num = (2.0f * m12 + C1) * (2.0f * ((XY) - m12) + C2);    \
        const float den = (m1s + m2s + C1) * (((XX) - m1s) + ((YY) - m2s) + C2); \
        local += num * __builtin_amdgcn_rcpf(den); }   /* den >= 9e-8 */
    SSIM_T(m1_0, m2_0, xx0, yy0, xy0)
    SSIM_T(m1_1, m2_1, xx1, yy1, xy1)
    SSIM_T(m1_2, m2_2, xx2, yy2, xy2)
    SSIM_T(m1_3, m2_3, xx3, yy3, xy3)
#undef SSIM_T

    // ---- Block reduction: wave shuffle -> LDS -> one store (or atomic) per block
    #pragma unroll
    for (int off = 32; off > 0; off >>= 1)
        local += __shfl_down(local, off, 64);
    if ((tid & 63) == 0) wsum[tid >> 6] = local;
    __syncthreads();
    if (tid == 0) {
        const double blk = (double)wsum[0] + (double)wsum[1]
                         + (double)wsum[2] + (double)wsum[3];
        if (use_atomic) {
            atomicAdd(part, blk);
        } else {
            const int bflat = blockIdx.x
                            + gridDim.x * (blockIdx.y + gridDim.y * blockIdx.z);
            part[bflat] = blk;
        }
    }
}

__global__ void ssim_reduce(const double* __restrict__ part, float* __restrict__ out,
                            int n)
{
    __shared__ double s[256];
    double t = 0.0;
    for (int i = threadIdx.x; i < n; i += 256) t += part[i];
    s[threadIdx.x] = t;
    __syncthreads();
    for (int off = 128; off > 0; off >>= 1) {
        if (threadIdx.x < off) s[threadIdx.x] += s[threadIdx.x + off];
        __syncthreads();
    }
    if (threadIdx.x == 0)
        out[0] = (float)(s[0] / (double)((size_t)NC * IMG_H * IMG_W));
}

extern "C" void kernel_launch(void* const* d_in, const int* in_sizes, int n_in,
                              void* d_out, int out_size, void* d_ws, size_t ws_size,
                              hipStream_t stream)
{
    const float* x = (const float*)d_in[0];
    const float* y = (const float*)d_in[1];
    const float* w = (const float*)d_in[2];
    double* part = (double*)d_ws;

    const bool fits = ws_size >= (size_t)NBLK * sizeof(double);
    dim3 grid(IMG_W / TW, IMG_H / TH, NC);   // (8, 32, 48) = 12288 blocks

    if (fits) {
        // every block writes its own slot; no memset, no atomics
        ssim_fused<<<grid, 256, 0, stream>>>(x, y, w, part, 0);
        ssim_reduce<<<1, 256, 0, stream>>>(part, (float*)d_out, NBLK);
    } else {
        hipMemsetAsync(d_ws, 0, sizeof(double), stream);
        ssim_fused<<<grid, 256, 0, stream>>>(x, y, w, part, 1);
        ssim_reduce<<<1, 256, 0, stream>>>(part, (float*)d_out, 1);
    }
}

// Round 11
// 188.751 us; speedup vs baseline: 1.2929x; 1.2815x over previous
//
#include <hip/hip_runtime.h>

// SSIM, fused separable-conv single pass + reduce.
// x,y: [16,3,512,512] f32; window: [3,1,11,11] f32 (separable Gaussian).
// Output: scalar mean SSIM (f32).
//
// V10 = V9 with __launch_bounds__(256, 4)  [single-variable change].
// THE SPILL WAS THE LAUNCH BOUNDS, NOT THE CODE. Empirical allocator cap
// on gfx950 is ~256/w (rounded down to 8), HALF the nominal 512/w:
//   w=8 -> 32 VGPR (V4, 368 MB spill); w=6 -> 40 (V5-V9, 150-174 MB spill,
//   three different phase-H rewrites all pinned at exactly 40);
//   w=4 -> >=52 (V0 emitted 52, spill-free).
// The f16 dot2 phase-H needs ~55-60 live regs -> at cap 40 the compiler
// spills ~15 regs ~= 50 B/thread = the measured 150-174 MB WRITE_SIZE.
// w=4 gives cap ~64: spill-free, and <=64 VGPR keeps the 8-waves/SIMD
// hardware occupancy step available (LDS 13.3 KB allows 12 blocks/CU).
//
// Proven content kept (V9): no classes/unions/struct-loads in f16 path;
// LDS planes raw ushort; f16 cvt via __builtin_bit_cast (RTNE); H-conv via
// v_dot2_f32_f16 (f32 accum, products exact); f16-tap renormalization
// h/Sum(h) (kills V3's 4.9e-4 bias); SSIM division via v_rcp_f32
// (den >= 9e-8); phase V direct global loads, f32 taps/accum.

#define IMG_H 512
#define IMG_W 512
#define NC    48            // 16 batches * 3 channels

constexpr int TW = 64;      // output tile width
constexpr int TH = 16;      // output tile height
constexpr int NBLK = (IMG_W / TW) * (IMG_H / TH) * NC;   // 12288

typedef _Float16 v2h   __attribute__((ext_vector_type(2)));
typedef unsigned u32x4 __attribute__((ext_vector_type(4)));
typedef unsigned u32x2 __attribute__((ext_vector_type(2)));

static __device__ __forceinline__ v2h as_h2(unsigned u) {
    return __builtin_bit_cast(v2h, u);
}
static __device__ __forceinline__ unsigned short f16bits(float f) {
    return __builtin_bit_cast(unsigned short, (_Float16)f);   // RTNE cvt
}

__global__ __launch_bounds__(256, 4)
void ssim_fused(const float* __restrict__ x, const float* __restrict__ y,
                const float* __restrict__ w, double* __restrict__ part,
                int use_atomic)
{
    // f16 vconv planes as raw ushort: 80 halves/row = 160 B. Cols 0..74 from
    // phase V, col 75 zeroed (touched by zero-coeff dot2 pairs), 76..79 unused.
    __shared__ __align__(16) unsigned short vvS[5][TH][80];
    __shared__ float wsum[4];

    const int tid = threadIdx.x;
    const int x0 = blockIdx.x * TW - 8;    // virtual staged col 0
    const int y0 = blockIdx.y * TH - 5;    // virtual staged row 0
    const float* __restrict__ xp = x + (size_t)blockIdx.z * (IMG_H * IMG_W);
    const float* __restrict__ yp = y + (size_t)blockIdx.z * (IMG_H * IMG_W);

    // 1D gaussian from window row 5: g[k] = w[55+k]/sqrt(w[60]).
    float g[11];
    {
        const float g5inv = 1.0f / sqrtf(w[55 + 5]);
        #pragma unroll
        for (int k = 0; k < 11; ++k)
            g[k] = __uint_as_float(
                (unsigned)__builtin_amdgcn_readfirstlane(
                    (int)__float_as_uint(w[55 + k] * g5inv)));
    }
    // Named half2 tap pairs (vector literals, no class) + exact f32 sum of
    // the rounded taps for renormalization.
    const v2h g2_0 = v2h{(_Float16)g[0], (_Float16)g[1]};
    const v2h g2_1 = v2h{(_Float16)g[2], (_Float16)g[3]};
    const v2h g2_2 = v2h{(_Float16)g[4], (_Float16)g[5]};
    const v2h g2_3 = v2h{(_Float16)g[6], (_Float16)g[7]};
    const v2h g2_4 = v2h{(_Float16)g[8], (_Float16)g[9]};
    const v2h g2_5 = v2h{(_Float16)g[10], (_Float16)0.0f};
    const float hsum =
        (float)g2_0[0] + (float)g2_0[1] + (float)g2_1[0] + (float)g2_1[1] +
        (float)g2_2[0] + (float)g2_2[1] + (float)g2_3[0] + (float)g2_3[1] +
        (float)g2_4[0] + (float)g2_4[1] + (float)g2_5[0];
    const float hnorm = 1.0f / hsum;               // uniform, once per block

    // Accessed region: rows y0 .. y0+25, cols x0+2 .. x0+76.
    const bool interior = (y0 >= 0) & (y0 + 25 < IMG_H)
                        & (x0 + 2 >= 0) & (x0 + 76 < IMG_W);

    // ---- Phase V: vertical 11-tap conv of {x,y,xx,yy,xy} at image col
    //      x0+c+2, 4-row register blocking, inputs straight from global.
    //      Results stored to LDS as f16 bits (RTNE scalar cvt, no class).
    for (int t = tid; t < 75 * 4; t += 256) {
        const int c   = t % 75;
        const int r0  = (t / 75) << 2;
        const int gc  = x0 + c + 2;
        const int gr0 = y0 + r0;
        float xv[14], yv[14], xxv[14], yyv[14], xyv[14];
        if (interior) {
            const unsigned base = (unsigned)(gr0 * IMG_W + gc);
            #pragma unroll
            for (int k = 0; k < 14; ++k) {
                const float a = xp[base + (unsigned)(k * IMG_W)];
                const float b = yp[base + (unsigned)(k * IMG_W)];
                xv[k] = a; yv[k] = b;
                xxv[k] = a * a; yyv[k] = b * b; xyv[k] = a * b;
            }
        } else {
            const int  cc  = min(max(gc, 0), IMG_W - 1);
            const bool okc = ((unsigned)gc < (unsigned)IMG_W);
            #pragma unroll
            for (int k = 0; k < 14; ++k) {
                const int  gr = gr0 + k;
                const int  cr = min(max(gr, 0), IMG_H - 1);
                const bool ok = okc & ((unsigned)gr < (unsigned)IMG_H);
                const unsigned idx = (unsigned)(cr * IMG_W + cc);
                const float a = ok ? xp[idx] : 0.0f;   // zero padding
                const float b = ok ? yp[idx] : 0.0f;
                xv[k] = a; yv[k] = b;
                xxv[k] = a * a; yyv[k] = b * b; xyv[k] = a * b;
            }
        }
        #pragma unroll
        for (int j = 0; j < 4; ++j) {
            float s0 = 0.f, s1 = 0.f, s2 = 0.f, s3 = 0.f, s4 = 0.f;
            #pragma unroll
            for (int k = 0; k < 11; ++k) {
                const float gk = g[k];
                s0 = fmaf(gk, xv[j + k],  s0);
                s1 = fmaf(gk, yv[j + k],  s1);
                s2 = fmaf(gk, xxv[j + k], s2);
                s3 = fmaf(gk, yyv[j + k], s3);
                s4 = fmaf(gk, xyv[j + k], s4);
            }
            vvS[0][r0 + j][c] = f16bits(s0);
            vvS[1][r0 + j][c] = f16bits(s1);
            vvS[2][r0 + j][c] = f16bits(s2);
            vvS[3][r0 + j][c] = f16bits(s3);
            vvS[4][r0 + j][c] = f16bits(s4);
        }
    }
    // col 75 is consumed (x 0 coeff) by dot2 pairs -> must be finite (+0.0)
    if (tid < 80) vvS[tid >> 4][tid & 15][75] = 0;
    __syncthreads();

    // ---- Phase H: horizontal 11-tap conv via dot2 + SSIM.
    // Thread -> (row r, 4-col group i). Output col j = 4i+t taps vv cols
    // j+1..j+11. u32 word m of the row holds cols (2m, 2m+1). Words
    // 2i..2i+7 needed (+1 for shifts); base w0 = 4*(i>>1) (16B aligned),
    // odd parity via named cndmask selects. Everything is a named SSA
    // scalar / ext_vector: no alloca anywhere.
    const int r   = tid >> 4;           // 0..15
    const int i   = tid & 15;           // 0..15
    const int w0  = (i >> 1) << 2;      // u32 word base, 16B aligned
    const bool odd = (i & 1) != 0;

    float m1_0, m1_1, m1_2, m1_3;
    float m2_0, m2_1, m2_2, m2_3;
    float xx0, xx1, xx2, xx3;
    float yy0, yy1, yy2, yy3;
    float xy0, xy1, xy2, xy3;

#define HSTEP(GP, WS, WB1, WS1, WB2) \
        a0 = __builtin_amdgcn_fdot2(as_h2(WS),  GP, a0, false); \
        a1 = __builtin_amdgcn_fdot2(as_h2(WB1), GP, a1, false); \
        a2 = __builtin_amdgcn_fdot2(as_h2(WS1), GP, a2, false); \
        a3 = __builtin_amdgcn_fdot2(as_h2(WB2), GP, a3, false);

#define HCONV(PLANE, O0, O1, O2, O3) { \
        const unsigned* rowp = (const unsigned*)&vvS[PLANE][r][0]; \
        const u32x4 A0 = *(const u32x4*)(rowp + w0); \
        const u32x4 A1 = *(const u32x4*)(rowp + w0 + 4); \
        const u32x2 A2 = *(const u32x2*)(rowp + w0 + 8); \
        const unsigned u0 = A0[0], u1 = A0[1], u2 = A0[2], u3 = A0[3]; \
        const unsigned u4 = A1[0], u5 = A1[1], u6 = A1[2], u7 = A1[3]; \
        const unsigned u8 = A2[0], u9 = A2[1]; \
        const unsigned b0 = odd ? u2 : u0, b1 = odd ? u3 : u1; \
        const unsigned b2 = odd ? u4 : u2, b3 = odd ? u5 : u3; \
        const unsigned b4 = odd ? u6 : u4, b5 = odd ? u7 : u5; \
        const unsigned b6 = odd ? u8 : u6, b7 = odd ? u9 : u7; \
        const unsigned s0 = (b0 >> 16) | (b1 << 16); \
        const unsigned s1 = (b1 >> 16) | (b2 << 16); \
        const unsigned s2 = (b2 >> 16) | (b3 << 16); \
        const unsigned s3 = (b3 >> 16) | (b4 << 16); \
        const unsigned s4 = (b4 >> 16) | (b5 << 16); \
        const unsigned s5 = (b5 >> 16) | (b6 << 16); \
        const unsigned s6 = (b6 >> 16) | (b7 << 16); \
        float a0 = 0.f, a1 = 0.f, a2 = 0.f, a3 = 0.f; \
        HSTEP(g2_0, s0, b1, s1, b2) \
        HSTEP(g2_1, s1, b2, s2, b3) \
        HSTEP(g2_2, s2, b3, s3, b4) \
        HSTEP(g2_3, s3, b4, s4, b5) \
        HSTEP(g2_4, s4, b5, s5, b6) \
        HSTEP(g2_5, s5, b6, s6, b7) \
        O0 = a0 * hnorm; O1 = a1 * hnorm; \
        O2 = a2 * hnorm; O3 = a3 * hnorm; }

    HCONV(0, m1_0, m1_1, m1_2, m1_3)
    HCONV(1, m2_0, m2_1, m2_2, m2_3)
    HCONV(2, xx0, xx1, xx2, xx3)
    HCONV(3, yy0, yy1, yy2, yy3)
    HCONV(4, xy0, xy1, xy2, xy3)
#undef HCONV
#undef HSTEP

    const float C1 = 1e-4f;   // 0.01^2
    const float C2 = 9e-4f;   // 0.03^2
    float local = 0.0f;
#define SSIM_T(M1, M2, XX, YY, XY) { \
        const float m1s = (M1) * (M1), m2s = (M2) * (M2), m12 = (M1) * (M2); \
        const float num = (2.0f * m12 + C1) * (2.0f * ((XY) - m12) + C2);    \
        const float den = (m1s + m2s + C1) * (((XX) - m1s) + ((YY) - m2s) + C2); \
        local += num * __builtin_amdgcn_rcpf(den); }   /* den >= 9e-8 */
    SSIM_T(m1_0, m2_0, xx0, yy0, xy0)
    SSIM_T(m1_1, m2_1, xx1, yy1, xy1)
    SSIM_T(m1_2, m2_2, xx2, yy2, xy2)
    SSIM_T(m1_3, m2_3, xx3, yy3, xy3)
#undef SSIM_T

    // ---- Block reduction: wave shuffle -> LDS -> one store (or atomic) per block
    #pragma unroll
    for (int off = 32; off > 0; off >>= 1)
        local += __shfl_down(local, off, 64);
    if ((tid & 63) == 0) wsum[tid >> 6] = local;
    __syncthreads();
    if (tid == 0) {
        const double blk = (double)wsum[0] + (double)wsum[1]
                         + (double)wsum[2] + (double)wsum[3];
        if (use_atomic) {
            atomicAdd(part, blk);
        } else {
            const int bflat = blockIdx.x
                            + gridDim.x * (blockIdx.y + gridDim.y * blockIdx.z);
            part[bflat] = blk;
        }
    }
}

__global__ void ssim_reduce(const double* __restrict__ part, float* __restrict__ out,
                            int n)
{
    __shared__ double s[256];
    double t = 0.0;
    for (int i = threadIdx.x; i < n; i += 256) t += part[i];
    s[threadIdx.x] = t;
    __syncthreads();
    for (int off = 128; off > 0; off >>= 1) {
        if (threadIdx.x < off) s[threadIdx.x] += s[threadIdx.x + off];
        __syncthreads();
    }
    if (threadIdx.x == 0)
        out[0] = (float)(s[0] / (double)((size_t)NC * IMG_H * IMG_W));
}

extern "C" void kernel_launch(void* const* d_in, const int* in_sizes, int n_in,
                              void* d_out, int out_size, void* d_ws, size_t ws_size,
                              hipStream_t stream)
{
    const float* x = (const float*)d_in[0];
    const float* y = (const float*)d_in[1];
    const float* w = (const float*)d_in[2];
    double* part = (double*)d_ws;

    const bool fits = ws_size >= (size_t)NBLK * sizeof(double);
    dim3 grid(IMG_W / TW, IMG_H / TH, NC);   // (8, 32, 48) = 12288 blocks

    if (fits) {
        // every block writes its own slot; no memset, no atomics
        ssim_fused<<<grid, 256, 0, stream>>>(x, y, w, part, 0);
        ssim_reduce<<<1, 256, 0, stream>>>(part, (float*)d_out, NBLK);
    } else {
        hipMemsetAsync(d_ws, 0, sizeof(double), stream);
        ssim_fused<<<grid, 256, 0, stream>>>(x, y, w, part, 1);
        ssim_reduce<<<1, 256, 0, stream>>>(part, (float*)d_out, 1);
    }
}